// Round 4
// baseline (207.528 us; speedup 1.0000x reference)
//
#include <hip/hip_runtime.h>
#include <cmath>

// Shapes fixed by the reference: data [32,128,80,80] int32, scale 0.0625.
#define NB  32
#define NC  128
#define NHW 6400            // 80*80, contiguous per (b,c)
#define TPB 128             // threads per block = pixels per block
#define BPB (NHW / TPB)     // 50 blocks per batch image (no batch straddle)

// One pixel per thread: all 128 channels in-registers (packed 4x int8 -> 32
// VGPRs), max + exp-sum + epilogue fully thread-local. No cross-thread
// reductions, no barriers except after the LUT build. Loads/stores are dword,
// 64 consecutive lanes -> 256 B contiguous per instruction.

__global__ __launch_bounds__(TPB) void qsoftmax_kernel(
    const int* __restrict__ data,
    const float* __restrict__ dscale,
    float* __restrict__ out) {
#pragma clang fp contract(off)
  __shared__ float exp_tab_f[256];   // quantized exp (integer-valued float)
  __shared__ float recip_tab[256];   // quantized 1/v table, region (0.1, 250)

  const int t = threadIdx.x;
  const float ds = dscale[0];        // 0.0625

  // ---- build LUTs: 2 entries per thread (identical math to absmax=0 ver) ----
#pragma unroll
  for (int e2 = 0; e2 < 2; ++e2) {
    const int idx = t + e2 * TPB;
    const float EXP_SCALE_F = (float)(2.0 / 65535.0);
    float x = (float)(-idx) * ds;
    float e;
    if (x >= 0.0f) {
      float y0 = expf(0.0f), y1 = expf(1.0f);
      e = rintf((y0 + x * ((y1 - y0) / 1.0f)) / EXP_SCALE_F);
    } else if (x >= -10.0f) {
      float delta = 10.0f / 255.0f;
      float idxf = rintf((x + 10.0f) * 25.5f);
      idxf = fminf(fmaxf(idxf, 0.0f), 255.0f);
      float xs = -10.0f + idxf * delta;
      e = rintf((float)exp((double)xs) / EXP_SCALE_F);
    } else {
      float delta = 10.0f / 255.0f;
      float idxf = rintf((x + 20.0f) * 25.5f);
      idxf = fminf(fmaxf(idxf, 0.0f), 255.0f);
      float xs = -20.0f + idxf * delta;
      e = rintf((float)exp((double)xs) / EXP_SCALE_F);
    }
    e = fminf(fmaxf(e, -32768.0f), 32767.0f);
    exp_tab_f[idx] = e;              // integer-valued float in [0, 32767]

    const float RECIP_SCALE_F = (float)((1.0 / 0.1) * 2.0 / 65535.0);
    float deltar = (250.0f - 0.1f) / 255.0f;
    float xs = 0.1f + (float)idx * deltar;
    float r = rintf((1.0f / xs) / RECIP_SCALE_F);
    r = fminf(fmaxf(r, -32768.0f), 32767.0f);
    recip_tab[idx] = r;
  }
  __syncthreads();

  // ---- this thread's pixel ----
  const int b    = blockIdx.x / BPB;
  const int hw   = (blockIdx.x % BPB) * TPB + t;
  const int base = b * NC * NHW + hw;

  // ---- pass 0: load 128 channels, running max, pack raw bytes ----
  int pd[32];
  int q = -128;
#pragma unroll
  for (int g = 0; g < 32; ++g) {
    int v0 = data[base + (4 * g + 0) * NHW];
    int v1 = data[base + (4 * g + 1) * NHW];
    int v2 = data[base + (4 * g + 2) * NHW];
    int v3 = data[base + (4 * g + 3) * NHW];
    q = max(q, max(max(v0, v1), max(v2, v3)));
    pd[g] = (v0 & 255) | ((v1 & 255) << 8) | ((v2 & 255) << 16) |
            (int)((unsigned)(v3 & 255) << 24);
  }

  // ---- in-place: packed bytes -> packed j = (q - c) mod 256 (exact, j<=255)
  // Byte-wise guarded subtraction: even bytes with borrow-guard bits at
  // bit8/bit24, odd bytes with guard at bit16 (byte3's borrow exits bit31).
  {
    unsigned qq   = (unsigned)q & 255u;
    unsigned Qe_g = (((qq << 16) | qq) + 0x01000100u);
    unsigned Qo_g = Qe_g << 8;
#pragma unroll
    for (int g = 0; g < 32; ++g) {
      unsigned p  = (unsigned)pd[g];
      unsigned je = (Qe_g - (p & 0x00FF00FFu)) & 0x00FF00FFu;
      unsigned jo = (Qo_g - (p & 0xFF00FF00u)) & 0xFF00FF00u;
      pd[g] = (int)(je | jo);
    }
  }

  // ---- pass A: sum of exp over channels (f32 exact: integers < 2^24) ----
  float s0 = 0.f, s1 = 0.f, s2 = 0.f, s3 = 0.f;
#pragma unroll
  for (int g = 0; g < 32; ++g) {
    unsigned J = (unsigned)pd[g];
    s0 += exp_tab_f[J & 255u];
    s1 += exp_tab_f[(J >> 8) & 255u];
    s2 += exp_tab_f[(J >> 16) & 255u];
    s3 += exp_tab_f[J >> 24];
  }
  float tot = (s0 + s1) + (s2 + s3);

  // ---- reciprocal of shifted sum (thread-local, exact ref math) ----
  const float DIV_SCALE_F = (float)((2.0 / 65535.0) * 128.0); // exp_scale*2^7
  const float RIDX_K_F    = (float)(255.0 / (250.0 - 0.1));
  float ss = rintf(tot * 0.0078125f);
  ss = fminf(fmaxf(ss, -32768.0f), 32767.0f);
  float v = ss * DIV_SCALE_F;
  float idxf = rintf((v - 0.1f) * RIDX_K_F);
  idxf = fminf(fmaxf(idxf, 0.0f), 255.0f);
  const float rq = recip_tab[(int)idxf];

  // ---- epilogue: out = clip(round((e*rq)*K), -128, 127) * OUT_SCALE ----
  const float K_F = (float)((2.0 / 65535.0) * ((1.0 / 0.1) * 2.0 / 65535.0) / (2.0 / 255.0));
  const float OUT_SCALE_F = (float)(2.0 / 255.0);
#pragma unroll
  for (int g = 0; g < 32; ++g) {
    unsigned J = (unsigned)pd[g];
    float e0 = exp_tab_f[J & 255u];
    float e1 = exp_tab_f[(J >> 8) & 255u];
    float e2 = exp_tab_f[(J >> 16) & 255u];
    float e3 = exp_tab_f[J >> 24];
    float o0 = fminf(fmaxf(rintf((e0 * rq) * K_F), -128.0f), 127.0f) * OUT_SCALE_F;
    float o1 = fminf(fmaxf(rintf((e1 * rq) * K_F), -128.0f), 127.0f) * OUT_SCALE_F;
    float o2 = fminf(fmaxf(rintf((e2 * rq) * K_F), -128.0f), 127.0f) * OUT_SCALE_F;
    float o3 = fminf(fmaxf(rintf((e3 * rq) * K_F), -128.0f), 127.0f) * OUT_SCALE_F;
    __builtin_nontemporal_store(o0, &out[base + (4 * g + 0) * NHW]);
    __builtin_nontemporal_store(o1, &out[base + (4 * g + 1) * NHW]);
    __builtin_nontemporal_store(o2, &out[base + (4 * g + 2) * NHW]);
    __builtin_nontemporal_store(o3, &out[base + (4 * g + 3) * NHW]);
  }
}

extern "C" void kernel_launch(void* const* d_in, const int* in_sizes, int n_in,
                              void* d_out, int out_size, void* d_ws, size_t ws_size,
                              hipStream_t stream) {
  const int* data     = (const int*)d_in[0];
  const float* dscale = (const float*)d_in[1];
  float* out          = (float*)d_out;
  (void)in_sizes; (void)n_in; (void)d_ws; (void)ws_size; (void)out_size;

  dim3 grid(NB * BPB);   // 32 * 50 = 1600 blocks of 128 threads (1 pixel/thread)
  qsoftmax_kernel<<<grid, TPB, 0, stream>>>(data, dscale, out);
}

// Round 5
// 194.090 us; speedup vs baseline: 1.0692x; 1.0692x over previous
//
#include <hip/hip_runtime.h>
#include <cmath>

// Shapes fixed by the reference: data [32,128,80,80] int32, scale 0.0625.
#define NB   32
#define NC   128
#define NHW  6400           // 80*80, contiguous per (b,c)
#define TPB  1024           // 16 channel-groups x 64 pixel-quads
#define PIXB 256            // pixels per block -> 1KB per channel-visit per wave
#define GPB  (NHW / PIXB)   // 25 blocks per image

typedef float vfloat4 __attribute__((ext_vector_type(4)));

// Thread t: k = t>>6 owns channels {k, k+16, ..., k+112};
//           p = t&63 owns pixels {4p .. 4p+3} within the block's 256-pixel range.
// Each wave = one k, p=0..63 -> every global load/store is 64 consecutive
// int4/float4 = 1KB contiguous (16 of these per block step cover all DRAM
// channel-interleave residues; the old 64-px blocks hit only 4 of 16).
// Payload: 8 packed ints (4x int8 bytes). Two barriers total.

__global__ __launch_bounds__(TPB) void qsoftmax_kernel(
    const int* __restrict__ data,
    const float* __restrict__ dscale,
    float* __restrict__ out) {
#pragma clang fp contract(off)
  __shared__ float exp_tab_f[256];    // quantized exp (integer-valued float)
  __shared__ float recip_tab[256];    // quantized 1/v table, region (0.1, 250)
  __shared__ int4  red_m[16][64];     // [k][p] partial max
  __shared__ float4 red_s[16][64];    // [k][p] partial sum (integer-valued f32)

  const int t = threadIdx.x;
  const int k = t >> 6;
  const int p = t & 63;

  const float ds = dscale[0];         // 0.0625

  // ---- build LUTs: threads 0..255, entry t (identical math to absmax=0) ----
  if (t < 256) {
    const float EXP_SCALE_F = (float)(2.0 / 65535.0);
    float x = (float)(-t) * ds;
    float e;
    if (x >= 0.0f) {
      float y0 = expf(0.0f), y1 = expf(1.0f);
      e = rintf((y0 + x * ((y1 - y0) / 1.0f)) / EXP_SCALE_F);
    } else if (x >= -10.0f) {
      float delta = 10.0f / 255.0f;
      float idxf = rintf((x + 10.0f) * 25.5f);
      idxf = fminf(fmaxf(idxf, 0.0f), 255.0f);
      float xs = -10.0f + idxf * delta;
      e = rintf((float)exp((double)xs) / EXP_SCALE_F);
    } else {
      float delta = 10.0f / 255.0f;
      float idxf = rintf((x + 20.0f) * 25.5f);
      idxf = fminf(fmaxf(idxf, 0.0f), 255.0f);
      float xs = -20.0f + idxf * delta;
      e = rintf((float)exp((double)xs) / EXP_SCALE_F);
    }
    e = fminf(fmaxf(e, -32768.0f), 32767.0f);
    exp_tab_f[t] = e;                 // integer-valued float in [0, 32767]

    const float RECIP_SCALE_F = (float)((1.0 / 0.1) * 2.0 / 65535.0);
    float deltar = (250.0f - 0.1f) / 255.0f;
    float xs = 0.1f + (float)t * deltar;
    float r = rintf((1.0f / xs) / RECIP_SCALE_F);
    r = fminf(fmaxf(r, -32768.0f), 32767.0f);
    recip_tab[t] = r;
  }

  // ---- load 8 channels x 4 pixels (1KB/wave-instr); pack bytes; local max ----
  const int blk   = blockIdx.x;
  const int b     = blk / GPB;
  const int base4 = b * NC * (NHW / 4) + (blk % GPB) * (PIXB / 4) + p;
  const int4* g4  = (const int4*)data;

  int pd[8];
  int4 m = make_int4(-128, -128, -128, -128);
#pragma unroll
  for (int i = 0; i < 8; ++i) {
    int4 v = g4[base4 + (16 * i + k) * (NHW / 4)];
    m.x = max(m.x, v.x); m.y = max(m.y, v.y);
    m.z = max(m.z, v.z); m.w = max(m.w, v.w);
    pd[i] = (v.x & 255) | ((v.y & 255) << 8) | ((v.z & 255) << 16) |
            (int)((unsigned)(v.w & 255) << 24);
  }
  red_m[k][p] = m;
  __syncthreads();   // also covers the LUT build

  // ---- every thread reduces the 16 partial maxes (conflict-free b128) ----
  int4 q = red_m[0][p];
#pragma unroll
  for (int kk = 1; kk < 16; ++kk) {
    int4 r = red_m[kk][p];
    q.x = max(q.x, r.x); q.y = max(q.y, r.y);
    q.z = max(q.z, r.z); q.w = max(q.w, r.w);
  }

  // ---- in-place packed bytes -> packed j = (q - c) mod 256, per-pixel q ----
  // Even bytes (pixels x,z) with borrow guards at bit8/bit24; odd bytes
  // (pixels y,w) guard at bit16, byte3's borrow exits bit31 (mod 2^32).
  {
    unsigned Qe = (((unsigned)q.x & 255u) | (((unsigned)q.z & 255u) << 16)) + 0x01000100u;
    unsigned Qo = ((((unsigned)q.y & 255u) << 8) | (((unsigned)q.w & 255u) << 24)) + 0x00010000u;
#pragma unroll
    for (int i = 0; i < 8; ++i) {
      unsigned pp = (unsigned)pd[i];
      unsigned je = (Qe - (pp & 0x00FF00FFu)) & 0x00FF00FFu;
      unsigned jo = (Qo - (pp & 0xFF00FF00u)) & 0xFF00FF00u;
      pd[i] = (int)(je | jo);
    }
  }

  // ---- partial sum of exp over this thread's 8 channels (f32 exact) ----
  float sx = 0.f, sy = 0.f, sz = 0.f, sw = 0.f;
#pragma unroll
  for (int i = 0; i < 8; ++i) {
    unsigned J = (unsigned)pd[i];
    sx += exp_tab_f[J & 255u];
    sy += exp_tab_f[(J >> 8) & 255u];
    sz += exp_tab_f[(J >> 16) & 255u];
    sw += exp_tab_f[J >> 24];
  }
  red_s[k][p] = make_float4(sx, sy, sz, sw);
  __syncthreads();

  // ---- every thread reduces the 16 partial sums; thread-local recip ----
  float4 tot = red_s[0][p];
#pragma unroll
  for (int kk = 1; kk < 16; ++kk) {
    float4 r = red_s[kk][p];
    tot.x += r.x; tot.y += r.y; tot.z += r.z; tot.w += r.w;
  }
  const float DIV_SCALE_F = (float)((2.0 / 65535.0) * 128.0); // exp_scale*2^7
  const float RIDX_K_F    = (float)(255.0 / (250.0 - 0.1));
  float rq[4];
  {
    float tv[4] = {tot.x, tot.y, tot.z, tot.w};
#pragma unroll
    for (int j = 0; j < 4; ++j) {
      float ss = rintf(tv[j] * 0.0078125f);
      ss = fminf(fmaxf(ss, -32768.0f), 32767.0f);
      float v = ss * DIV_SCALE_F;
      float idxf = rintf((v - 0.1f) * RIDX_K_F);
      idxf = fminf(fmaxf(idxf, 0.0f), 255.0f);
      rq[j] = recip_tab[(int)idxf];
    }
  }

  // ---- epilogue: re-gather exp; out = clip(round((e*rq)*K))*OUT_SCALE ----
  const float K_F = (float)((2.0 / 65535.0) * ((1.0 / 0.1) * 2.0 / 65535.0) / (2.0 / 255.0));
  const float OUT_SCALE_F = (float)(2.0 / 255.0);
  vfloat4* o4 = (vfloat4*)out;
#pragma unroll
  for (int i = 0; i < 8; ++i) {
    unsigned J = (unsigned)pd[i];
    float e0 = exp_tab_f[J & 255u];
    float e1 = exp_tab_f[(J >> 8) & 255u];
    float e2 = exp_tab_f[(J >> 16) & 255u];
    float e3 = exp_tab_f[J >> 24];
    vfloat4 o;
    o.x = fminf(fmaxf(rintf((e0 * rq[0]) * K_F), -128.0f), 127.0f) * OUT_SCALE_F;
    o.y = fminf(fmaxf(rintf((e1 * rq[1]) * K_F), -128.0f), 127.0f) * OUT_SCALE_F;
    o.z = fminf(fmaxf(rintf((e2 * rq[2]) * K_F), -128.0f), 127.0f) * OUT_SCALE_F;
    o.w = fminf(fmaxf(rintf((e3 * rq[3]) * K_F), -128.0f), 127.0f) * OUT_SCALE_F;
    __builtin_nontemporal_store(o, &o4[base4 + (16 * i + k) * (NHW / 4)]);
  }
}

extern "C" void kernel_launch(void* const* d_in, const int* in_sizes, int n_in,
                              void* d_out, int out_size, void* d_ws, size_t ws_size,
                              hipStream_t stream) {
  const int* data     = (const int*)d_in[0];
  const float* dscale = (const float*)d_in[1];
  float* out          = (float*)d_out;
  (void)in_sizes; (void)n_in; (void)d_ws; (void)ws_size; (void)out_size;

  dim3 grid(NB * GPB);   // 32 * 25 = 800 blocks of 1024 threads
  qsoftmax_kernel<<<grid, TPB, 0, stream>>>(data, dscale, out);
}